// Round 1
// baseline (473.890 us; speedup 1.0000x reference)
//
#include <hip/hip_runtime.h>

// Problem constants
#define BN_TOTAL 8192   // B*N
#define KTOK 32
#define DDIM 256
#define TDIM 256

typedef float f32x4 __attribute__((ext_vector_type(4)));
typedef short bf16x8 __attribute__((ext_vector_type(8)));

__device__ __forceinline__ unsigned short f2bf(float f){
    unsigned int u = __builtin_bit_cast(unsigned int, f);
    u = u + 0x7fffu + ((u >> 16) & 1u);   // RNE
    return (unsigned short)(u >> 16);
}
__device__ __forceinline__ float bf2f(unsigned short h){
    unsigned int u = ((unsigned int)h) << 16;
    return __builtin_bit_cast(float, u);
}
// tanh-approx gelu == x * sigmoid(2*0.7978845608*(x + 0.044715 x^3))  (exact identity)
__device__ __forceinline__ float gelu_tanh(float x){
    float y = 1.5957691216057308f * (x + 0.044715f * x * x * x);
    return x / (1.0f + __expf(-y));
}

// B-fragment pack position for mfma_f32_16x16x32_bf16:
// lane l needs B[k = kt*32 + (l>>4)*8 + j][n = nt*16 + (l&15)], j=0..7 contiguous.
__device__ __forceinline__ int packpos(int k, int n, int NT){
    int kt = k >> 5, quad = (k >> 3) & 3, j = k & 7;
    int nt = n >> 4, nl = n & 15;
    return ((kt * NT + nt) * 64 + quad * 16 + nl) * 8 + j;
}

// ---- kernel 1: pack W_h[0:256] (bf16 frag layout), W_logit (padded N=16), b_combo ----
__global__ __launch_bounds__(256) void pack_weights(const float* __restrict__ Wh,
        const float* __restrict__ Wlogit, const float* __restrict__ b_ego,
        const float* __restrict__ b_h,
        unsigned short* __restrict__ Bp1, unsigned short* __restrict__ BpL,
        float* __restrict__ b_combo){
    int bid = blockIdx.x, tid = threadIdx.x;
    if (bid < 64){
        int base = (bid * 256 + tid) * 4;
        for (int e = base; e < base + 4; ++e){
            int k = e >> 8, n = e & 255;
            Bp1[packpos(k, n, 16)] = f2bf(Wh[k * 256 + n]);
        }
    } else if (bid == 64){
        for (int e = tid * 16; e < tid * 16 + 16; ++e){
            int k = e >> 4, n = e & 15;
            float v = (n < 4) ? Wlogit[k * 4 + n] : 0.0f;
            BpL[packpos(k, n, 1)] = f2bf(v);
        }
    } else {
        // b_combo[c] = b_h[c] + sum_j b_ego[j] * W_h2[j][c]
        float acc = b_h[tid];
        for (int j = 0; j < 256; ++j) acc += b_ego[j] * Wh[(256 + j) * 256 + tid];
        b_combo[tid] = acc;
    }
}

// ---- kernel 2: W_combo = W_ego @ W_h[256:512], packed bf16 frag layout ----
__global__ __launch_bounds__(256) void combo_pack(const float* __restrict__ Wego,
        const float* __restrict__ Wh, unsigned short* __restrict__ Bpc){
    __shared__ float row[256];
    int k = blockIdx.x, n = threadIdx.x;
    row[n] = Wego[k * 256 + n];
    __syncthreads();
    float acc = 0.f;
    const float4* row4 = (const float4*)row;
    for (int j4 = 0; j4 < 64; ++j4){
        float4 e = row4[j4];
        int j = j4 * 4;
        acc += e.x * Wh[(256 + j) * 256 + n];
        acc += e.y * Wh[(257 + j) * 256 + n];
        acc += e.z * Wh[(258 + j) * 256 + n];
        acc += e.w * Wh[(259 + j) * 256 + n];
    }
    Bpc[packpos(k, n, 16)] = f2bf(acc);
}

// ---- kernel 3: ego_term[8192][256] = bf16(ego_ctx @ W_combo + b_combo), MFMA ----
__global__ __launch_bounds__(256) void ego_gemm(const float* __restrict__ ego_ctx,
        const unsigned short* __restrict__ Bpc, const float* __restrict__ b_combo,
        unsigned short* __restrict__ ego_term){
    int w = threadIdx.x >> 6, l = threadIdx.x & 63;
    int row = blockIdx.x * 64 + w * 16 + (l & 15);
    f32x4 acc[16];
    #pragma unroll
    for (int i = 0; i < 16; ++i) acc[i] = 0;
    #pragma unroll
    for (int kt = 0; kt < 8; ++kt){
        int k0 = kt * 32 + ((l >> 4) << 3);
        const float* ap = ego_ctx + row * 256 + k0;
        float4 x0 = *(const float4*)ap;
        float4 x1 = *(const float4*)(ap + 4);
        bf16x8 a;
        a[0]=(short)f2bf(x0.x); a[1]=(short)f2bf(x0.y); a[2]=(short)f2bf(x0.z); a[3]=(short)f2bf(x0.w);
        a[4]=(short)f2bf(x1.x); a[5]=(short)f2bf(x1.y); a[6]=(short)f2bf(x1.z); a[7]=(short)f2bf(x1.w);
        #pragma unroll
        for (int nt = 0; nt < 16; ++nt){
            bf16x8 b = *(const bf16x8*)&Bpc[((kt * 16 + nt) * 64 + l) * 8];
            acc[nt] = __builtin_amdgcn_mfma_f32_16x16x32_bf16(a, b, acc[nt], 0, 0, 0);
        }
    }
    int rq = (l >> 4) * 4, col = l & 15;
    int rbase = blockIdx.x * 64 + w * 16 + rq;
    #pragma unroll
    for (int nt = 0; nt < 16; ++nt){
        int n = nt * 16 + col;
        float bc = b_combo[n];
        #pragma unroll
        for (int rg = 0; rg < 4; ++rg)
            ego_term[(rbase + rg) * 256 + n] = f2bf(acc[nt][rg] + bc);
    }
}

// ---- kernel 4: fused LN -> GEMM -> gelu -> logits -> masked softmax -> readout ----
__global__ __launch_bounds__(256) void main_fused(const float* __restrict__ inv,
        const float* __restrict__ rin, const float* __restrict__ uin,
        const int* __restrict__ mask, const float* __restrict__ ln_s,
        const float* __restrict__ ln_b, const float* __restrict__ b_logit,
        const unsigned short* __restrict__ Bp1, const unsigned short* __restrict__ BpL,
        const unsigned short* __restrict__ ego_term, float* __restrict__ out){

    __shared__ unsigned short Albs[64 * 264];   // A tile (bf16), stride 264 -> 2-way LDS conflicts only
    __shared__ float ego_s[2][256];
    __shared__ float logit_s[64 * 4];
    __shared__ float alpha_s[64 * 4];

    int tid = threadIdx.x;
    int w = tid >> 6, l = tid & 63;
    int T0 = blockIdx.x * 64;     // global token-row base (2 groups x 32 tokens)
    int bn0 = blockIdx.x * 2;     // (b,n) group base

    // stage ego_term rows for the 2 groups
    for (int i = tid; i < 512; i += 256)
        ego_s[i >> 8][i & 255] = bf2f(ego_term[bn0 * 256 + i]);

    // --- LayerNorm: wave w handles rows w*16 .. w*16+15; lane holds cols 4l..4l+3 ---
    {
        float4 sc = *(const float4*)&ln_s[l * 4];
        float4 bs = *(const float4*)&ln_b[l * 4];
        int r0 = w * 16;
        const float* base = inv + (T0 + r0) * 256 + l * 4;
        float4 cur = *(const float4*)base;
        #pragma unroll
        for (int rr = 0; rr < 16; ++rr){
            float4 nxt = cur;
            if (rr < 15) nxt = *(const float4*)(base + (rr + 1) * 256);
            float s  = cur.x + cur.y + cur.z + cur.w;
            float s2 = cur.x*cur.x + cur.y*cur.y + cur.z*cur.z + cur.w*cur.w;
            #pragma unroll
            for (int off = 32; off >= 1; off >>= 1){
                s  += __shfl_xor(s,  off);
                s2 += __shfl_xor(s2, off);
            }
            float mean = s * (1.0f / 256.0f);
            float var  = s2 * (1.0f / 256.0f) - mean * mean;
            float rstd = rsqrtf(var + 1e-6f);
            ushort4 o;
            o.x = f2bf((cur.x - mean) * rstd * sc.x + bs.x);
            o.y = f2bf((cur.y - mean) * rstd * sc.y + bs.y);
            o.z = f2bf((cur.z - mean) * rstd * sc.z + bs.z);
            o.w = f2bf((cur.w - mean) * rstd * sc.w + bs.w);
            *(ushort4*)&Albs[(r0 + rr) * 264 + l * 4] = o;
            cur = nxt;
        }
    }
    __syncthreads();

    // --- GEMM: C(64x256) = A(64x256) @ W_h1(256x256); wave w owns n-range [64w,64w+64) ---
    f32x4 acc[4][4];
    #pragma unroll
    for (int a = 0; a < 4; ++a)
        #pragma unroll
        for (int b = 0; b < 4; ++b) acc[a][b] = 0;
    {
        int kq = (l >> 4) << 3, ml = l & 15;
        #pragma unroll
        for (int kt = 0; kt < 8; ++kt){
            int ko = kt * 32 + kq;
            bf16x8 af[4], bfv[4];
            #pragma unroll
            for (int mt = 0; mt < 4; ++mt)
                af[mt] = *(const bf16x8*)&Albs[(mt * 16 + ml) * 264 + ko];
            #pragma unroll
            for (int i = 0; i < 4; ++i)
                bfv[i] = *(const bf16x8*)&Bp1[((kt * 16 + (w * 4 + i)) * 64 + l) * 8];
            #pragma unroll
            for (int mt = 0; mt < 4; ++mt)
                #pragma unroll
                for (int i = 0; i < 4; ++i)
                    acc[mt][i] = __builtin_amdgcn_mfma_f32_16x16x32_bf16(af[mt], bfv[i], acc[mt][i], 0, 0, 0);
        }
    }
    __syncthreads();   // all A reads done before overwrite with h

    // --- epilogue: h = gelu(C + ego_term) -> back into Albs (bf16) ---
    {
        int col = l & 15, rq = (l >> 4) * 4;
        #pragma unroll
        for (int mt = 0; mt < 4; ++mt){
            int g = mt >> 1;
            #pragma unroll
            for (int i = 0; i < 4; ++i){
                int n = (w * 4 + i) * 16 + col;
                float eg = ego_s[g][n];
                #pragma unroll
                for (int rg = 0; rg < 4; ++rg){
                    float x = acc[mt][i][rg] + eg;
                    Albs[(mt * 16 + rq + rg) * 264 + n] = f2bf(gelu_tanh(x));
                }
            }
        }
    }
    __syncthreads();

    // --- logits = h @ W_logit (padded to 16 cols); wave w owns m-tile w ---
    {
        int kq = (l >> 4) << 3, ml = l & 15;
        f32x4 lacc = 0;
        #pragma unroll
        for (int kt = 0; kt < 8; ++kt){
            bf16x8 a = *(const bf16x8*)&Albs[(w * 16 + ml) * 264 + kt * 32 + kq];
            bf16x8 b = *(const bf16x8*)&BpL[(kt * 64 + l) * 8];
            lacc = __builtin_amdgcn_mfma_f32_16x16x32_bf16(a, b, lacc, 0, 0, 0);
        }
        if (ml < 4){
            float bl = b_logit[ml];
            int rq = (l >> 4) * 4;
            #pragma unroll
            for (int rg = 0; rg < 4; ++rg)
                logit_s[(w * 16 + rq + rg) * 4 + ml] = lacc[rg] + bl;
        }
    }
    __syncthreads();

    // --- masked softmax over k (32 lanes per (g,h)) ---
    {
        int g = w >> 1;
        int h = ((w & 1) << 1) + (l >> 5);
        int k = l & 31;
        int valid = mask[T0 + g * 32 + k] != 0;
        float lg = logit_s[(g * 32 + k) * 4 + h];
        float val = valid ? lg : -3.0e38f;
        float mx = val;
        #pragma unroll
        for (int off = 16; off >= 1; off >>= 1)
            mx = fmaxf(mx, __shfl_xor(mx, off));
        float e = valid ? __expf(lg - mx) : 0.0f;
        float ssum = e;
        #pragma unroll
        for (int off = 16; off >= 1; off >>= 1)
            ssum += __shfl_xor(ssum, off);
        float a = (ssum > 0.f) ? e / ssum : 0.0f;
        alpha_s[(g * 32 + k) * 4 + h] = a;
        out[196608 + (T0 + g * 32 + k) * 4 + h] = a;
    }
    __syncthreads();

    // --- v_r / v_u readout: 48 threads, one (g, r/u, h, d) each ---
    if (tid < 48){
        int g = tid / 24, rem = tid % 24;
        int which = rem / 12, hd = rem % 12;
        int h = hd / 3, d = hd % 3;
        const float* src = which ? uin : rin;
        const float* sp = src + (T0 + g * 32) * 3 + d;
        float acc2 = 0.f;
        #pragma unroll
        for (int k = 0; k < 32; ++k)
            acc2 += alpha_s[(g * 32 + k) * 4 + h] * sp[k * 3];
        out[which * 98304 + (bn0 + g) * 12 + hd] = acc2;
    }
}

extern "C" void kernel_launch(void* const* d_in, const int* in_sizes, int n_in,
                              void* d_out, int out_size, void* d_ws, size_t ws_size,
                              hipStream_t stream){
    const float* inv    = (const float*)d_in[0];
    const float* ego    = (const float*)d_in[1];
    const float* rin    = (const float*)d_in[2];
    const float* uin    = (const float*)d_in[3];
    const int*   mask   = (const int*)  d_in[4];
    const float* Wego   = (const float*)d_in[5];
    const float* b_ego  = (const float*)d_in[6];
    const float* ln_s   = (const float*)d_in[7];
    const float* ln_b   = (const float*)d_in[8];
    const float* Wh     = (const float*)d_in[9];
    const float* b_h    = (const float*)d_in[10];
    const float* Wlogit = (const float*)d_in[11];
    const float* b_lg   = (const float*)d_in[12];
    float* out = (float*)d_out;

    unsigned short* wsu = (unsigned short*)d_ws;
    unsigned short* Bp1 = wsu;                     // 65536 bf16  (128 KB)
    unsigned short* Bpc = wsu + 65536;             // 65536 bf16  (128 KB)
    unsigned short* BpL = wsu + 131072;            // 4096 bf16   (8 KB)
    float* b_combo      = (float*)(wsu + 135168);  // 256 f32     (1 KB)
    unsigned short* ego_term = wsu + 135680;       // 8192*256 bf16 (4 MB)

    pack_weights<<<66, 256, 0, stream>>>(Wh, Wlogit, b_ego, b_h, Bp1, BpL, b_combo);
    combo_pack<<<256, 256, 0, stream>>>(Wego, Wh, Bpc);
    ego_gemm<<<128, 256, 0, stream>>>(ego, Bpc, b_combo, ego_term);
    main_fused<<<4096, 256, 0, stream>>>(inv, rin, uin, mask, ln_s, ln_b, b_lg,
                                         Bp1, BpL, ego_term, out);
}

// Round 3
// 455.747 us; speedup vs baseline: 1.0398x; 1.0398x over previous
//
#include <hip/hip_runtime.h>

typedef float f32x4 __attribute__((ext_vector_type(4)));
typedef short bf16x8 __attribute__((ext_vector_type(8)));

__device__ __forceinline__ unsigned short f2bf(float f){
    unsigned int u = __builtin_bit_cast(unsigned int, f);
    u = u + 0x7fffu + ((u >> 16) & 1u);   // RNE
    return (unsigned short)(u >> 16);
}
__device__ __forceinline__ float bf2f(unsigned short h){
    unsigned int u = ((unsigned int)h) << 16;
    return __builtin_bit_cast(float, u);
}
__device__ __forceinline__ unsigned int pk2(float a, float b){
    return (unsigned int)f2bf(a) | ((unsigned int)f2bf(b) << 16);
}
// gelu(tanh approx) == x * sigmoid(1.5957691*(x + 0.044715 x^3))  (exact identity)
__device__ __forceinline__ float gelu_f(float x){
    float t = x * x;
    float u = fmaf(0.044715f, t, 1.0f);
    float y = 1.5957691216057308f * x * u;
    float e = __expf(-y);
    return x * __builtin_amdgcn_rcpf(1.0f + e);
}

// B-fragment pack position for mfma_f32_16x16x32_bf16:
// lane l needs B[k = kt*32 + (l>>4)*8 + j][n = nt*16 + (l&15)], j=0..7 contiguous.
__device__ __forceinline__ int packpos(int k, int n, int NT){
    int kt = k >> 5, quad = (k >> 3) & 3, j = k & 7;
    int nt = n >> 4, nl = n & 15;
    return ((kt * NT + nt) * 64 + quad * 16 + nl) * 8 + j;
}

// ---- prep: all weight packing in one kernel (grid = 323) ----
// bid 0..63   : Bp1 = bf16(scale[k] * W_h1[k][n])   (scale folded in)
// bid 64      : BpL = W_logit padded to 16 cols
// bid 65      : b_combo = b_h + b_ego@W_h2 + ln_bias@W_h1
// bid 66      : v1 = colsum of bf16-rounded scale*W_h1
// bid 67..322 : Bpc = W_ego @ W_h2 row (bid-67), packed bf16
__global__ __launch_bounds__(256) void prep(const float* __restrict__ Wh,
        const float* __restrict__ Wlogit, const float* __restrict__ Wego,
        const float* __restrict__ b_ego, const float* __restrict__ b_h,
        const float* __restrict__ ln_s, const float* __restrict__ ln_b,
        unsigned short* __restrict__ Bp1, unsigned short* __restrict__ BpL,
        unsigned short* __restrict__ Bpc, float* __restrict__ b_combo,
        float* __restrict__ v1){
    __shared__ float rowbuf[256];
    int bid = blockIdx.x, tid = threadIdx.x;
    if (bid < 64){
        int base = (bid * 256 + tid) * 4;
        int k = base >> 8;
        float sc = ln_s[k];
        for (int e = base; e < base + 4; ++e){
            int n = e & 255;
            Bp1[packpos(k, n, 16)] = f2bf(sc * Wh[k * 256 + n]);
        }
    } else if (bid == 64){
        for (int e = tid * 16; e < tid * 16 + 16; ++e){
            int k = e >> 4, n = e & 15;
            float v = (n < 4) ? Wlogit[k * 4 + n] : 0.0f;
            BpL[packpos(k, n, 1)] = f2bf(v);
        }
    } else if (bid == 65){
        float acc = b_h[tid];
        for (int j = 0; j < 256; ++j) acc += b_ego[j] * Wh[(256 + j) * 256 + tid];
        for (int k = 0; k < 256; ++k) acc += ln_b[k] * Wh[k * 256 + tid];
        b_combo[tid] = acc;
    } else if (bid == 66){
        float acc = 0.f;
        for (int k = 0; k < 256; ++k)
            acc += bf2f(f2bf(ln_s[k] * Wh[k * 256 + tid]));
        v1[tid] = acc;
    } else {
        int k = bid - 67;
        rowbuf[tid] = Wego[k * 256 + tid];
        __syncthreads();
        float acc = 0.f;
        const float4* row4 = (const float4*)rowbuf;
        for (int j4 = 0; j4 < 64; ++j4){
            float4 e = row4[j4];
            int j = j4 * 4;
            acc += e.x * Wh[(256 + j) * 256 + tid];
            acc += e.y * Wh[(257 + j) * 256 + tid];
            acc += e.z * Wh[(258 + j) * 256 + tid];
            acc += e.w * Wh[(259 + j) * 256 + tid];
        }
        Bpc[packpos(k, tid, 16)] = f2bf(acc);
    }
}

// ---- ego_gemm: ego_term[8192][256] = bf16(ego_ctx @ W_combo + b_combo) ----
// grid 512, 16 rows/block; wave w owns n-tiles w*4..w*4+3
__global__ __launch_bounds__(256) void ego_gemm(const float* __restrict__ ego_ctx,
        const unsigned short* __restrict__ Bpc, const float* __restrict__ b_combo,
        unsigned short* __restrict__ ego_term){
    const int tid = threadIdx.x, w = tid >> 6, l = tid & 63;
    const int m0 = blockIdx.x * 16;
    const int row = m0 + (l & 15);
    const int kq = (l >> 4) << 3;
    f32x4 acc[4];
    #pragma unroll
    for (int j = 0; j < 4; ++j) acc[j] = 0;
    #pragma unroll
    for (int kt = 0; kt < 8; ++kt){
        const float* ap = ego_ctx + row * 256 + kt * 32 + kq;
        float4 x0 = *(const float4*)ap;
        float4 x1 = *(const float4*)(ap + 4);
        uint4 pu = {pk2(x0.x, x0.y), pk2(x0.z, x0.w), pk2(x1.x, x1.y), pk2(x1.z, x1.w)};
        bf16x8 a = __builtin_bit_cast(bf16x8, pu);
        #pragma unroll
        for (int j = 0; j < 4; ++j){
            int nt = w * 4 + j;
            bf16x8 b = *(const bf16x8*)&Bpc[((kt * 16 + nt) * 64 + l) * 8];
            acc[j] = __builtin_amdgcn_mfma_f32_16x16x32_bf16(a, b, acc[j], 0, 0, 0);
        }
    }
    const int rq = (l >> 4) << 2, colc = l & 15;
    #pragma unroll
    for (int j = 0; j < 4; ++j){
        int n = (w * 4 + j) * 16 + colc;
        float bc = b_combo[n];
        #pragma unroll
        for (int rg = 0; rg < 4; ++rg)
            ego_term[(m0 + rq + rg) * 256 + n] = f2bf(acc[j][rg] + bc);
    }
}

// ---- main: stage bf16 X -> GEMM(X@W1') + MFMA stats -> LN-folded gelu epilogue
//      -> logits MFMA -> masked softmax -> readout ----
__global__ __launch_bounds__(256) void main_fused(const float* __restrict__ inv,
        const float* __restrict__ rin, const float* __restrict__ uin,
        const int* __restrict__ mask, const float* __restrict__ b_logit,
        const unsigned short* __restrict__ Bp1, const unsigned short* __restrict__ BpL,
        const unsigned short* __restrict__ ego_term, const float* __restrict__ v1g,
        float* __restrict__ out){

    __shared__ unsigned short Albs[64 * 264];   // X tile then h tile (bf16), stride 264
    __shared__ float2 stats_s[64];              // {rstd, rstd*mean} per row
    __shared__ float logit_s[256];
    __shared__ float alpha_s[256];

    const int tid = threadIdx.x;
    const int w = tid >> 6, l = tid & 63;
    const int T0 = blockIdx.x * 64;
    const int bn0 = blockIdx.x * 2;
    const int col = l & 15;
    const int kq = (l >> 4) << 3;

    // --- stage raw X as bf16 (coalesced, no stats here) ---
    {
        const int r0 = w * 16;
        const float* base = inv + (T0 + r0) * 256 + l * 4;
        #pragma unroll
        for (int rr = 0; rr < 16; ++rr){
            float4 c = *(const float4*)(base + rr * 256);
            uint2 p;
            p.x = pk2(c.x, c.y);
            p.y = pk2(c.z, c.w);
            *(uint2*)&Albs[(r0 + rr) * 264 + l * 4] = p;
        }
    }
    // --- per-lane epilogue constants straight from global (L2-resident) ---
    float v1r[4], egv[2][4];
    #pragma unroll
    for (int i = 0; i < 4; ++i){
        int n = w * 64 + i * 16 + col;
        v1r[i]    = v1g[n];
        egv[0][i] = bf2f(ego_term[(bn0    ) * 256 + n]);
        egv[1][i] = bf2f(ego_term[(bn0 + 1) * 256 + n]);
    }
    __syncthreads();

    // --- GEMM: Craw(64x256) = X @ W1'; wave w owns n-range [64w,64w+64).
    //     Stats for m-tile w ride along on the MFMA pipe:
    //     gram diag (sumsq) via mfma(af,af), rowsum via mfma(af,ones). ---
    f32x4 acc[4][4];
    #pragma unroll
    for (int a = 0; a < 4; ++a)
        #pragma unroll
        for (int b = 0; b < 4; ++b) acc[a][b] = 0;
    f32x4 gacc = 0, sacc = 0;
    bf16x8 ones;
    #pragma unroll
    for (int j = 0; j < 8; ++j) ones[j] = (short)0x3F80;

    #pragma unroll
    for (int kt = 0; kt < 8; ++kt){
        const int ko = kt * 32 + kq;
        bf16x8 af[4], bv[4];
        #pragma unroll
        for (int mt = 0; mt < 4; ++mt)
            af[mt] = *(const bf16x8*)&Albs[(mt * 16 + col) * 264 + ko];
        #pragma unroll
        for (int i = 0; i < 4; ++i)
            bv[i] = *(const bf16x8*)&Bp1[((kt * 16 + (w * 4 + i)) * 64 + l) * 8];
        #pragma unroll
        for (int mt = 0; mt < 4; ++mt){
            if (mt == w){   // wave-uniform branch
                gacc = __builtin_amdgcn_mfma_f32_16x16x32_bf16(af[mt], af[mt], gacc, 0, 0, 0);
                sacc = __builtin_amdgcn_mfma_f32_16x16x32_bf16(af[mt], ones,   sacc, 0, 0, 0);
            }
            #pragma unroll
            for (int i = 0; i < 4; ++i)
                acc[mt][i] = __builtin_amdgcn_mfma_f32_16x16x32_bf16(af[mt], bv[i], acc[mt][i], 0, 0, 0);
        }
    }
    // --- stats finalize: the 16 diag-holding lanes write {rstd, rstd*mean} ---
    if ((col >> 2) == (l >> 4)){
        int rg = col & 3;
        float mean = sacc[rg] * (1.0f / 256.0f);
        float var  = gacc[rg] * (1.0f / 256.0f) - mean * mean;
        float rstd = rsqrtf(var + 1e-6f);
        stats_s[w * 16 + col] = float2{rstd, rstd * mean};
    }
    __syncthreads();   // A reads done + stats visible

    // --- epilogue: h = gelu(rstd*Craw - (rstd*mean)*v1 + ego) -> back into Albs ---
    {
        const int rq = (l >> 4) << 2;
        #pragma unroll
        for (int mt = 0; mt < 4; ++mt){
            const int g = mt >> 1;
            float2 st[4];
            #pragma unroll
            for (int rg = 0; rg < 4; ++rg) st[rg] = stats_s[mt * 16 + rq + rg];
            #pragma unroll
            for (int i = 0; i < 4; ++i){
                const int n = w * 64 + i * 16 + col;
                const float base_t = egv[g][i];
                #pragma unroll
                for (int rg = 0; rg < 4; ++rg){
                    float x = fmaf(st[rg].x, acc[mt][i][rg],
                                   fmaf(-st[rg].y, v1r[i], base_t));
                    Albs[(mt * 16 + rq + rg) * 264 + n] = f2bf(gelu_f(x));
                }
            }
        }
    }
    __syncthreads();

    // --- logits = h @ W_logit (padded 16 cols); wave w owns m-tile w ---
    {
        f32x4 lacc = 0;
        #pragma unroll
        for (int kt = 0; kt < 8; ++kt){
            bf16x8 a = *(const bf16x8*)&Albs[(w * 16 + col) * 264 + kt * 32 + kq];
            bf16x8 b = *(const bf16x8*)&BpL[(kt * 64 + l) * 8];
            lacc = __builtin_amdgcn_mfma_f32_16x16x32_bf16(a, b, lacc, 0, 0, 0);
        }
        if (col < 4){
            float bl = b_logit[col];
            const int rq = (l >> 4) << 2;
            #pragma unroll
            for (int rg = 0; rg < 4; ++rg)
                logit_s[(w * 16 + rq + rg) * 4 + col] = lacc[rg] + bl;
        }
    }
    __syncthreads();

    // --- masked softmax over k (32 lanes per (group, head)) ---
    {
        int g = w >> 1;
        int h = ((w & 1) << 1) + (l >> 5);
        int k = l & 31;
        int valid = mask[T0 + g * 32 + k] != 0;
        float lg = logit_s[(g * 32 + k) * 4 + h];
        float val = valid ? lg : -3.0e38f;
        float mx = val;
        #pragma unroll
        for (int off = 16; off >= 1; off >>= 1)
            mx = fmaxf(mx, __shfl_xor(mx, off));
        float e = valid ? __expf(lg - mx) : 0.0f;
        float ssum = e;
        #pragma unroll
        for (int off = 16; off >= 1; off >>= 1)
            ssum += __shfl_xor(ssum, off);
        float a = (ssum > 0.f) ? e / ssum : 0.0f;
        alpha_s[(g * 32 + k) * 4 + h] = a;
        out[196608 + (T0 + g * 32 + k) * 4 + h] = a;
    }
    __syncthreads();

    // --- v_r / v_u readout ---
    if (tid < 48){
        int g = tid / 24, rem = tid % 24;
        int which = rem / 12, hd = rem % 12;
        int h = hd / 3, d = hd % 3;
        const float* src = which ? uin : rin;
        const float* sp = src + (T0 + g * 32) * 3 + d;
        float acc2 = 0.f;
        #pragma unroll
        for (int k = 0; k < 32; ++k)
            acc2 += alpha_s[(g * 32 + k) * 4 + h] * sp[k * 3];
        out[which * 98304 + (bn0 + g) * 12 + hd] = acc2;
    }
}

extern "C" void kernel_launch(void* const* d_in, const int* in_sizes, int n_in,
                              void* d_out, int out_size, void* d_ws, size_t ws_size,
                              hipStream_t stream){
    const float* inv    = (const float*)d_in[0];
    const float* ego    = (const float*)d_in[1];
    const float* rin    = (const float*)d_in[2];
    const float* uin    = (const float*)d_in[3];
    const int*   mask   = (const int*)  d_in[4];
    const float* Wego   = (const float*)d_in[5];
    const float* b_ego  = (const float*)d_in[6];
    const float* ln_s   = (const float*)d_in[7];
    const float* ln_b   = (const float*)d_in[8];
    const float* Wh     = (const float*)d_in[9];
    const float* b_h    = (const float*)d_in[10];
    const float* Wlogit = (const float*)d_in[11];
    const float* b_lg   = (const float*)d_in[12];
    float* out = (float*)d_out;

    unsigned short* wsu = (unsigned short*)d_ws;
    unsigned short* Bp1 = wsu;                       // 65536 bf16
    unsigned short* Bpc = wsu + 65536;               // 65536 bf16
    unsigned short* BpL = wsu + 131072;              // 4096 bf16
    float* b_combo      = (float*)(wsu + 135168);    // 256 f32
    float* v1           = (float*)(wsu + 135680);    // 256 f32
    unsigned short* ego_term = wsu + 136192;         // 8192*256 bf16

    prep<<<323, 256, 0, stream>>>(Wh, Wlogit, Wego, b_ego, b_h, ln_s, ln_b,
                                  Bp1, BpL, Bpc, b_combo, v1);
    ego_gemm<<<512, 256, 0, stream>>>(ego, Bpc, b_combo, ego_term);
    main_fused<<<4096, 256, 0, stream>>>(inv, rin, uin, mask, b_lg,
                                         Bp1, BpL, ego_term, v1, out);
}